// Round 1
// baseline (132.459 us; speedup 1.0000x reference)
//
#include <hip/hip_runtime.h>

// Problem constants (fixed by the reference file)
constexpr int B  = 2;
constexpr int X  = 128, Y = 128, Z = 128, C = 4;
constexpr int OX = 96,  OY = 96,  OZ = 96;
constexpr int NPTS = B * OX * OY * OZ;          // 1,769,472 output voxels
constexpr int PTS_PER_BATCH = OX * OY * OZ;     // 884,736

// One thread per output voxel; each handles all C=4 channels as a float4.
__global__ __launch_bounds__(256) void resampler_trilinear_kernel(
    const float* __restrict__ inp,       // [B, X, Y, Z, C] fp32
    const float* __restrict__ coords,    // [B, OX, OY, OZ, 3] fp32
    float4* __restrict__ out)            // [B, OX, OY, OZ, C] as float4
{
    const int tid = blockIdx.x * blockDim.x + threadIdx.x;
    if (tid >= NPTS) return;

    const int b = tid / PTS_PER_BATCH;

    // Coords: 3 consecutive floats per point (coalesced across lanes).
    const float cx = coords[(size_t)tid * 3 + 0];
    const float cy = coords[(size_t)tid * 3 + 1];
    const float cz = coords[(size_t)tid * 3 + 2];

    const float bx = floorf(cx), by = floorf(cy), bz = floorf(cz);
    const float wx0 = cx - bx, wy0 = cy - by, wz0 = cz - bz;  // frac (ceil weight)
    const float wx1 = 1.0f - wx0, wy1 = 1.0f - wy0, wz1 = 1.0f - wz0;

    // REPLICATE boundary: clamp the FLOAT base/ceil into [0, size-1], then cast
    // (matches the reference's jnp.clip on floats; handles base < 0 correctly).
    const int x0 = (int)fminf(fmaxf(bx,        0.0f), (float)(X - 1));
    const int x1 = (int)fminf(fmaxf(bx + 1.0f, 0.0f), (float)(X - 1));
    const int y0 = (int)fminf(fmaxf(by,        0.0f), (float)(Y - 1));
    const int y1 = (int)fminf(fmaxf(by + 1.0f, 0.0f), (float)(Y - 1));
    const int z0 = (int)fminf(fmaxf(bz,        0.0f), (float)(Z - 1));
    const int z1 = (int)fminf(fmaxf(bz + 1.0f, 0.0f), (float)(Z - 1));

    // Input as float4 (C=4 channels, 16B aligned & contiguous).
    const float4* in4 = (const float4*)inp + (size_t)b * X * Y * Z;
    const int xo0 = x0 * (Y * Z), xo1 = x1 * (Y * Z);
    const int yo0 = y0 * Z,       yo1 = y1 * Z;

    // Issue all 8 independent gathers; let them pipeline.
    const float4 v000 = in4[xo0 + yo0 + z0];
    const float4 v001 = in4[xo0 + yo0 + z1];
    const float4 v010 = in4[xo0 + yo1 + z0];
    const float4 v011 = in4[xo0 + yo1 + z1];
    const float4 v100 = in4[xo1 + yo0 + z0];
    const float4 v101 = in4[xo1 + yo0 + z1];
    const float4 v110 = in4[xo1 + yo1 + z0];
    const float4 v111 = in4[xo1 + yo1 + z1];

    // Factored trilinear: lerp z, then y, then x.
    // (corner with ceil bit set uses w0 of that dim, per reference)
    float4 r;
    #define LERP4(a, b, wA, wB, dst)                       \
        dst.x = (a).x * (wA) + (b).x * (wB);               \
        dst.y = (a).y * (wA) + (b).y * (wB);               \
        dst.z = (a).z * (wA) + (b).z * (wB);               \
        dst.w = (a).w * (wA) + (b).w * (wB);

    float4 c00, c01, c10, c11, c0, c1;
    LERP4(v000, v001, wz1, wz0, c00);
    LERP4(v010, v011, wz1, wz0, c01);
    LERP4(v100, v101, wz1, wz0, c10);
    LERP4(v110, v111, wz1, wz0, c11);
    LERP4(c00, c01, wy1, wy0, c0);
    LERP4(c10, c11, wy1, wy0, c1);
    LERP4(c0, c1, wx1, wx0, r);
    #undef LERP4

    out[tid] = r;   // coalesced 16B store
}

extern "C" void kernel_launch(void* const* d_in, const int* in_sizes, int n_in,
                              void* d_out, int out_size, void* d_ws, size_t ws_size,
                              hipStream_t stream) {
    const float* inp    = (const float*)d_in[0];
    const float* coords = (const float*)d_in[1];
    float4* out = (float4*)d_out;

    const int threads = 256;
    const int blocks  = (NPTS + threads - 1) / threads;   // 6912
    resampler_trilinear_kernel<<<blocks, threads, 0, stream>>>(inp, coords, out);
}